// Round 1
// baseline (861.770 us; speedup 1.0000x reference)
//
#include <hip/hip_runtime.h>
#include <hip/hip_bf16.h>

#define NN 100000
#define NE 1250000
#define DD 64
#define RR 16

typedef __attribute__((ext_vector_type(8))) short s16x8;
typedef __attribute__((ext_vector_type(4))) float f32x4;

static __device__ __forceinline__ unsigned short f2bf(float v) {
    __hip_bfloat16 h = __float2bfloat16(v);
    return __builtin_bit_cast(unsigned short, h);
}

// ---------------- sort-by-relation kernels ----------------

__global__ void zero_counters(int* hist) {
    if (threadIdx.x < RR) hist[threadIdx.x] = 0;
}

__global__ void hist_kernel(const int* __restrict__ et, int* __restrict__ hist) {
    __shared__ int lh[RR];
    if (threadIdx.x < RR) lh[threadIdx.x] = 0;
    __syncthreads();
    for (int e = blockIdx.x * blockDim.x + threadIdx.x; e < NE; e += gridDim.x * blockDim.x)
        atomicAdd(&lh[et[e]], 1);
    __syncthreads();
    if (threadIdx.x < RR) atomicAdd(&hist[threadIdx.x], lh[threadIdx.x]);
}

__global__ void scan_kernel(const int* __restrict__ hist, int* __restrict__ off, int* __restrict__ base) {
    // single thread: R=16, trivial
    if (blockIdx.x == 0 && threadIdx.x == 0) {
        int acc = 0;
        for (int r = 0; r < RR; ++r) {
            off[r] = acc;
            base[r] = acc;
            acc += hist[r];
        }
        off[RR] = acc;
    }
}

#define SCHUNK 4096
__global__ __launch_bounds__(256) void scatter_kernel(
    const int* __restrict__ src, const int* __restrict__ dst, const int* __restrict__ et,
    int* __restrict__ base, int* __restrict__ ssrc, int* __restrict__ sdst)
{
    __shared__ int lc[RR], gb[RR], lo[RR];
    int b0 = blockIdx.x * SCHUNK;
    int bend = min(b0 + SCHUNK, NE);
    if (threadIdx.x < RR) { lc[threadIdx.x] = 0; lo[threadIdx.x] = 0; }
    __syncthreads();
    for (int e = b0 + threadIdx.x; e < bend; e += 256)
        atomicAdd(&lc[et[e]], 1);
    __syncthreads();
    if (threadIdx.x < RR) gb[threadIdx.x] = atomicAdd(&base[threadIdx.x], lc[threadIdx.x]);
    __syncthreads();
    for (int e = b0 + threadIdx.x; e < bend; e += 256) {
        int r = et[e];
        int p = gb[r] + atomicAdd(&lo[r], 1);
        ssrc[p] = src[e];
        sdst[p] = dst[e];
    }
}

// ---------------- precision prep ----------------

// Wt[l][r][o][d] = bf16(W_l[r][d][o])   (transposed so B-frags are d-contiguous)
__global__ void prep_w(const float* __restrict__ W1, const float* __restrict__ W2,
                       unsigned short* __restrict__ wt)
{
    int i = blockIdx.x * 256 + threadIdx.x;
    if (i >= 2 * RR * DD * DD) return;
    int d = i & 63;
    int o = (i >> 6) & 63;
    int r = (i >> 12) & 15;
    int l = i >> 16;
    const float* W = l ? W2 : W1;
    wt[i] = f2bf(W[(r * DD + d) * DD + o]);
}

__global__ void prep_x(const float* __restrict__ x, unsigned short* __restrict__ xb) {
    int i = blockIdx.x * blockDim.x + threadIdx.x;
    if (i < NN * DD) xb[i] = f2bf(x[i]);
}

// ---------------- per-layer kernels ----------------

// out[n][o] = h[n]·sw[:,o] + b[o] (+ h[n][o] if residual)
__global__ void self_kernel(const float* __restrict__ h, const float* __restrict__ sw,
                            const float* __restrict__ bias, float* __restrict__ out,
                            int residual)
{
    int idx = blockIdx.x * blockDim.x + threadIdx.x;
    if (idx >= NN * DD) return;
    int o = idx & 63;
    const float* row = h + (idx & ~63);
    float acc = bias[o];
    if (residual) acc += row[o];
    #pragma unroll
    for (int d = 0; d < DD; ++d)
        acc += row[d] * sw[d * DD + o];
    out[idx] = acc;
}

// messages: per relation r (blockIdx.y), tiles of 16 edges, MFMA 16x16x32 bf16,
// scatter via HW fp32 atomics.
__global__ __launch_bounds__(256) void edge_kernel(
    const unsigned short* __restrict__ xb,   // [N][64] bf16
    const unsigned short* __restrict__ wt,   // [R][o][d] bf16 (this layer's plane)
    const int* __restrict__ ssrc, const int* __restrict__ sdst,
    const int* __restrict__ off,             // [R+1]
    float* __restrict__ out)
{
    const int r = blockIdx.y;
    __shared__ unsigned short lwt[64 * 72];   // W^T[r], padded stride 72 halves
    const unsigned short* wr = wt + r * (DD * DD);
    for (int i = threadIdx.x; i < DD * DD; i += 256) {
        int o = i >> 6, d = i & 63;
        lwt[o * 72 + d] = wr[i];
    }
    __syncthreads();

    const int s0 = off[r], s1 = off[r + 1];
    const int nedge = s1 - s0;
    if (nedge <= 0) return;
    const int ntile = (nedge + 15) >> 4;

    const int wid  = threadIdx.x >> 6;   // wave in block (0..3)
    const int lane = threadIdx.x & 63;
    const int c = lane & 15;             // col / A-row
    const int q = lane >> 4;             // quad

    // B fragments: B[k][n] = W[r][k=d][n=o] taken from lwt[o][d]
    s16x8 bfrag[4][2];
    #pragma unroll
    for (int nb = 0; nb < 4; ++nb)
        #pragma unroll
        for (int ks = 0; ks < 2; ++ks)
            bfrag[nb][ks] = *(const s16x8*)&lwt[(nb * 16 + c) * 72 + ks * 32 + q * 8];

    for (int t = blockIdx.x * 4 + wid; t < ntile; t += gridDim.x * 4) {
        const int e0 = s0 + (t << 4);
        // A: row m=c is edge e0+c, k = ks*32 + q*8 + j
        const int ea = e0 + c;
        const int srcn = (ea < s1) ? ssrc[ea] : ssrc[e0];
        const unsigned short* xrow = xb + srcn * DD;
        s16x8 a0 = *(const s16x8*)(xrow + q * 8);
        s16x8 a1 = *(const s16x8*)(xrow + 32 + q * 8);

        f32x4 acc[4];
        #pragma unroll
        for (int nb = 0; nb < 4; ++nb) {
            f32x4 a = {0.f, 0.f, 0.f, 0.f};
            a = __builtin_amdgcn_mfma_f32_16x16x32_bf16(a0, bfrag[nb][0], a, 0, 0, 0);
            a = __builtin_amdgcn_mfma_f32_16x16x32_bf16(a1, bfrag[nb][1], a, 0, 0, 0);
            acc[nb] = a;
        }

        // C layout: row = q*4 + v (edge), col = c (+16*nb)
        #pragma unroll
        for (int v = 0; v < 4; ++v) {
            const int er = e0 + q * 4 + v;
            if (er < s1) {
                const int dstn = sdst[er];
                float* op = out + dstn * DD + c;
                unsafeAtomicAdd(op +  0, acc[0][v]);
                unsafeAtomicAdd(op + 16, acc[1][v]);
                unsafeAtomicAdd(op + 32, acc[2][v]);
                unsafeAtomicAdd(op + 48, acc[3][v]);
            }
        }
    }
}

// relu in place + bf16 copy (for next layer's gathers)
__global__ void relu_bf(float* __restrict__ buf, unsigned short* __restrict__ hb) {
    int i = blockIdx.x * blockDim.x + threadIdx.x;
    if (i >= NN * DD) return;
    float v = buf[i];
    v = v > 0.f ? v : 0.f;
    buf[i] = v;
    hb[i] = f2bf(v);
}

__global__ void relu_only(float* __restrict__ buf) {
    int i = blockIdx.x * blockDim.x + threadIdx.x;
    if (i >= NN * DD) return;
    float v = buf[i];
    buf[i] = v > 0.f ? v : 0.f;
}

// ---------------- launch ----------------

extern "C" void kernel_launch(void* const* d_in, const int* in_sizes, int n_in,
                              void* d_out, int out_size, void* d_ws, size_t ws_size,
                              hipStream_t stream)
{
    (void)in_sizes; (void)n_in; (void)out_size; (void)ws_size;
    const float* x    = (const float*)d_in[0];
    const int*   ei   = (const int*)d_in[1];     // [2][E]
    const int*   et   = (const int*)d_in[2];
    const float* W1   = (const float*)d_in[3];
    const float* sw1  = (const float*)d_in[4];
    const float* b1   = (const float*)d_in[5];
    const float* W2   = (const float*)d_in[6];
    const float* sw2  = (const float*)d_in[7];
    const float* b2   = (const float*)d_in[8];
    float* out = (float*)d_out;

    const int* src = ei;
    const int* dst = ei + NE;

    char* ws = (char*)d_ws;
    float*          acc1 = (float*)(ws);                         // 25,600,000 B
    unsigned short* xb   = (unsigned short*)(ws + 25600000);     // 12,800,000 B
    unsigned short* h1b  = (unsigned short*)(ws + 38400000);     // 12,800,000 B
    unsigned short* wt   = (unsigned short*)(ws + 51200000);     //    262,144 B
    int*            ssrc = (int*)(ws + 51462144);                //  5,000,000 B
    int*            sdst = (int*)(ws + 56462144);                //  5,000,000 B
    int*            hist = (int*)(ws + 61462144);                //         64 B
    int*            base = (int*)(ws + 61462208);                //         64 B
    int*            off  = (int*)(ws + 61462272);                //         68 B

    const int NB_ELEM = (NN * DD + 255) / 256;   // 25000 blocks for N*D grids

    // sort by relation (once; reused by both layers)
    zero_counters<<<1, 64, 0, stream>>>(hist);
    hist_kernel<<<512, 256, 0, stream>>>(et, hist);
    scan_kernel<<<1, 64, 0, stream>>>(hist, off, base);
    scatter_kernel<<<(NE + SCHUNK - 1) / SCHUNK, 256, 0, stream>>>(src, dst, et, base, ssrc, sdst);

    // precision prep
    prep_w<<<(2 * RR * DD * DD + 255) / 256, 256, 0, stream>>>(W1, W2, wt);
    prep_x<<<NB_ELEM, 256, 0, stream>>>(x, xb);

    // ---- layer 1 (residual) ----
    self_kernel<<<NB_ELEM, 256, 0, stream>>>(x, sw1, b1, acc1, 1);
    edge_kernel<<<dim3(128, RR), 256, 0, stream>>>(xb, wt, ssrc, sdst, off, acc1);
    relu_bf<<<NB_ELEM, 256, 0, stream>>>(acc1, h1b);

    // ---- layer 2 (no residual) ----
    self_kernel<<<NB_ELEM, 256, 0, stream>>>(acc1, sw2, b2, out, 0);
    edge_kernel<<<dim3(128, RR), 256, 0, stream>>>(h1b, wt + RR * DD * DD, ssrc, sdst, off, out);
    relu_only<<<NB_ELEM, 256, 0, stream>>>(out);
}

// Round 2
// 612.130 us; speedup vs baseline: 1.4078x; 1.4078x over previous
//
#include <hip/hip_runtime.h>
#include <hip/hip_bf16.h>

#define NN 100000
#define NE 1250000
#define DD 64
#define RR 16
#define NP 17            // 16 relations + self plane
#define NTILE 6250       // NN/16

typedef __attribute__((ext_vector_type(8))) short s16x8;
typedef __attribute__((ext_vector_type(4))) float f32x4;

static __device__ __forceinline__ unsigned short f2bf(float v) {
    __hip_bfloat16 h = __float2bfloat16(v);
    return __builtin_bit_cast(unsigned short, h);
}
static __device__ __forceinline__ float bf2f(unsigned short u) {
    unsigned int w = ((unsigned int)u) << 16;
    return __builtin_bit_cast(float, w);
}

// ================= NEW PATH: dst-sorted gather-sum =================

// ---- sort by dst (counting sort, 100k bins) ----

__global__ void hist_dst(const int* __restrict__ dst, int* __restrict__ cnt) {
    int e = blockIdx.x * 256 + threadIdx.x;
    if (e < NE) atomicAdd(&cnt[dst[e]], 1);
}

// block-level exclusive scan of cnt -> rp, block totals -> part
__global__ __launch_bounds__(256) void scan1(const int* __restrict__ cnt,
                                             int* __restrict__ rp, int* __restrict__ part) {
    __shared__ int s[256];
    int i = blockIdx.x * 256 + threadIdx.x;
    int v = (i < NN) ? cnt[i] : 0;
    s[threadIdx.x] = v;
    __syncthreads();
    for (int off = 1; off < 256; off <<= 1) {
        int t = (threadIdx.x >= off) ? s[threadIdx.x - off] : 0;
        __syncthreads();
        s[threadIdx.x] += t;
        __syncthreads();
    }
    if (i < NN) rp[i] = s[threadIdx.x] - v;           // exclusive
    if (threadIdx.x == 255) part[blockIdx.x] = s[255];
}

#define NBLK_SCAN 391   // ceil(NN/256)
__global__ void scan2(int* __restrict__ part, int* __restrict__ rp) {
    __shared__ int s[NBLK_SCAN];
    if (threadIdx.x < NBLK_SCAN) s[threadIdx.x] = part[threadIdx.x];
    __syncthreads();
    if (threadIdx.x == 0) {
        int acc = 0;
        for (int b = 0; b < NBLK_SCAN; ++b) { int t = s[b]; s[b] = acc; acc += t; }
        rp[NN] = NE;
    }
    __syncthreads();
    if (threadIdx.x < NBLK_SCAN) part[threadIdx.x] = s[threadIdx.x];
}

__global__ void scan3(int* __restrict__ rp, const int* __restrict__ part, int* __restrict__ cur) {
    int i = blockIdx.x * 256 + threadIdx.x;
    if (i < NN) {
        int v = rp[i] + part[blockIdx.x];
        rp[i] = v;
        cur[i] = v;
    }
}

// scatter: sg[p] = rel*NN + src   (row index into the [plane][n] table)
__global__ void scatter_dst(const int* __restrict__ src, const int* __restrict__ dst,
                            const int* __restrict__ et, int* __restrict__ cur,
                            int* __restrict__ sg) {
    int e = blockIdx.x * 256 + threadIdx.x;
    if (e >= NE) return;
    int p = atomicAdd(&cur[dst[e]], 1);
    sg[p] = et[e] * NN + src[e];
}

// ---- precision prep ----

// wt2[l][p][o][d] = bf16( (p<16 ? W_l[p] : sw_l)[d][o] )
__global__ void prep_w2(const float* __restrict__ W1, const float* __restrict__ sw1,
                        const float* __restrict__ W2, const float* __restrict__ sw2,
                        unsigned short* __restrict__ wt) {
    int i = blockIdx.x * 256 + threadIdx.x;
    if (i >= 2 * NP * DD * DD) return;
    int d = i & 63;
    int o = (i >> 6) & 63;
    int p = (i >> 12) % NP;
    int l = i / (NP * DD * DD);
    const float* src;
    if (p < 16) src = (l ? W2 : W1) + p * DD * DD;
    else        src = (l ? sw2 : sw1);
    wt[i] = f2bf(src[d * DD + o]);
}

__global__ void prep_x2(const float* __restrict__ x, unsigned short* __restrict__ xb) {
    int i = blockIdx.x * blockDim.x + threadIdx.x;
    if (i < NN * DD) xb[i] = f2bf(x[i]);
}

// ---- kernel A: dense table  xW[p][n][o] = X @ Wp  (17 planes, bf16 out) ----
__global__ __launch_bounds__(256) void xw_kernel(
    const unsigned short* __restrict__ xb,   // [N][64] bf16
    const unsigned short* __restrict__ wt,   // [17][64][64] bf16 (o-major, d inner)
    unsigned short* __restrict__ tab)        // [17][N][64] bf16
{
    const int wid  = threadIdx.x >> 6;
    const int lane = threadIdx.x & 63;
    const int c = lane & 15;
    const int q = lane >> 4;
    const int t = blockIdx.x * 4 + wid;
    if (t >= NTILE) return;
    const int n0 = t * 16;

    // A fragments: row m=c is node n0+c
    const unsigned short* xrow = xb + (n0 + c) * DD;
    s16x8 a0 = *(const s16x8*)(xrow + q * 8);
    s16x8 a1 = *(const s16x8*)(xrow + 32 + q * 8);

    #pragma unroll 1
    for (int p = 0; p < NP; ++p) {
        const unsigned short* wp = wt + p * (DD * DD);
        f32x4 acc[4];
        #pragma unroll
        for (int nb = 0; nb < 4; ++nb) {
            s16x8 b0 = *(const s16x8*)(wp + (nb * 16 + c) * DD + q * 8);
            s16x8 b1 = *(const s16x8*)(wp + (nb * 16 + c) * DD + 32 + q * 8);
            f32x4 a = {0.f, 0.f, 0.f, 0.f};
            a = __builtin_amdgcn_mfma_f32_16x16x32_bf16(a0, b0, a, 0, 0, 0);
            a = __builtin_amdgcn_mfma_f32_16x16x32_bf16(a1, b1, a, 0, 0, 0);
            acc[nb] = a;
        }
        // D layout: row = q*4+v (node), col = nb*16+c
        unsigned short* ob = tab + ((size_t)p * NN + n0 + q * 4) * DD + c;
        #pragma unroll
        for (int v = 0; v < 4; ++v) {
            unsigned short* orow = ob + v * DD;
            orow[0]  = f2bf(acc[0][v]);
            orow[16] = f2bf(acc[1][v]);
            orow[32] = f2bf(acc[2][v]);
            orow[48] = f2bf(acc[3][v]);
        }
    }
}

// ---- kernel B: per-dst segment sum + self + bias (+res) + relu ----
__global__ __launch_bounds__(256) void agg_kernel(
    const unsigned short* __restrict__ tab,  // [17][N][64] bf16
    const int* __restrict__ rp,              // [N+1]
    const int* __restrict__ sg,              // [E] row index = rel*NN+src
    const float* __restrict__ bias,
    const float* __restrict__ xres,          // residual (fp32) or nullptr
    float* __restrict__ outf,                // fp32 out (layer 2) or nullptr
    unsigned short* __restrict__ outb)       // bf16 out (layer 1) or nullptr
{
    const int wid  = threadIdx.x >> 6;
    const int lane = threadIdx.x & 63;
    const int n = blockIdx.x * 4 + wid;      // 25000*4 == NN exactly
    const int o = lane;

    float acc = bias[o] + bf2f(tab[((size_t)16 * NN + n) * DD + o]);  // self plane
    if (xres) acc += xres[n * DD + o];

    int e  = rp[n];
    const int e1 = rp[n + 1];
    for (; e + 4 <= e1; e += 4) {
        int i0 = sg[e], i1 = sg[e + 1], i2 = sg[e + 2], i3 = sg[e + 3];
        float v0 = bf2f(tab[(size_t)i0 * DD + o]);
        float v1 = bf2f(tab[(size_t)i1 * DD + o]);
        float v2 = bf2f(tab[(size_t)i2 * DD + o]);
        float v3 = bf2f(tab[(size_t)i3 * DD + o]);
        acc += (v0 + v1) + (v2 + v3);
    }
    for (; e < e1; ++e)
        acc += bf2f(tab[(size_t)sg[e] * DD + o]);

    acc = fmaxf(acc, 0.f);
    if (outb) outb[n * DD + o] = f2bf(acc);
    if (outf) outf[n * DD + o] = acc;
}

// ================= OLD PATH (fallback if ws too small) =================

__global__ void zero_counters(int* hist) {
    if (threadIdx.x < RR) hist[threadIdx.x] = 0;
}

__global__ void hist_kernel(const int* __restrict__ et, int* __restrict__ hist) {
    __shared__ int lh[RR];
    if (threadIdx.x < RR) lh[threadIdx.x] = 0;
    __syncthreads();
    for (int e = blockIdx.x * blockDim.x + threadIdx.x; e < NE; e += gridDim.x * blockDim.x)
        atomicAdd(&lh[et[e]], 1);
    __syncthreads();
    if (threadIdx.x < RR) atomicAdd(&hist[threadIdx.x], lh[threadIdx.x]);
}

__global__ void scan_kernel(const int* __restrict__ hist, int* __restrict__ off, int* __restrict__ base) {
    if (blockIdx.x == 0 && threadIdx.x == 0) {
        int acc = 0;
        for (int r = 0; r < RR; ++r) { off[r] = acc; base[r] = acc; acc += hist[r]; }
        off[RR] = acc;
    }
}

#define SCHUNK 4096
__global__ __launch_bounds__(256) void scatter_kernel(
    const int* __restrict__ src, const int* __restrict__ dst, const int* __restrict__ et,
    int* __restrict__ base, int* __restrict__ ssrc, int* __restrict__ sdst)
{
    __shared__ int lc[RR], gb[RR], lo[RR];
    int b0 = blockIdx.x * SCHUNK;
    int bend = min(b0 + SCHUNK, NE);
    if (threadIdx.x < RR) { lc[threadIdx.x] = 0; lo[threadIdx.x] = 0; }
    __syncthreads();
    for (int e = b0 + threadIdx.x; e < bend; e += 256)
        atomicAdd(&lc[et[e]], 1);
    __syncthreads();
    if (threadIdx.x < RR) gb[threadIdx.x] = atomicAdd(&base[threadIdx.x], lc[threadIdx.x]);
    __syncthreads();
    for (int e = b0 + threadIdx.x; e < bend; e += 256) {
        int r = et[e];
        int p = gb[r] + atomicAdd(&lo[r], 1);
        ssrc[p] = src[e];
        sdst[p] = dst[e];
    }
}

__global__ void prep_w(const float* __restrict__ W1, const float* __restrict__ W2,
                       unsigned short* __restrict__ wt)
{
    int i = blockIdx.x * 256 + threadIdx.x;
    if (i >= 2 * RR * DD * DD) return;
    int d = i & 63;
    int o = (i >> 6) & 63;
    int r = (i >> 12) & 15;
    int l = i >> 16;
    const float* W = l ? W2 : W1;
    wt[i] = f2bf(W[(r * DD + d) * DD + o]);
}

__global__ void self_kernel(const float* __restrict__ h, const float* __restrict__ sw,
                            const float* __restrict__ bias, float* __restrict__ out,
                            int residual)
{
    int idx = blockIdx.x * blockDim.x + threadIdx.x;
    if (idx >= NN * DD) return;
    int o = idx & 63;
    const float* row = h + (idx & ~63);
    float acc = bias[o];
    if (residual) acc += row[o];
    #pragma unroll
    for (int d = 0; d < DD; ++d)
        acc += row[d] * sw[d * DD + o];
    out[idx] = acc;
}

__global__ __launch_bounds__(256) void edge_kernel(
    const unsigned short* __restrict__ xb,
    const unsigned short* __restrict__ wt,
    const int* __restrict__ ssrc, const int* __restrict__ sdst,
    const int* __restrict__ off,
    float* __restrict__ out)
{
    const int r = blockIdx.y;
    __shared__ unsigned short lwt[64 * 72];
    const unsigned short* wr = wt + r * (DD * DD);
    for (int i = threadIdx.x; i < DD * DD; i += 256) {
        int o = i >> 6, d = i & 63;
        lwt[o * 72 + d] = wr[i];
    }
    __syncthreads();

    const int s0 = off[r], s1 = off[r + 1];
    const int nedge = s1 - s0;
    if (nedge <= 0) return;
    const int ntile = (nedge + 15) >> 4;

    const int wid  = threadIdx.x >> 6;
    const int lane = threadIdx.x & 63;
    const int c = lane & 15;
    const int q = lane >> 4;

    s16x8 bfrag[4][2];
    #pragma unroll
    for (int nb = 0; nb < 4; ++nb)
        #pragma unroll
        for (int ks = 0; ks < 2; ++ks)
            bfrag[nb][ks] = *(const s16x8*)&lwt[(nb * 16 + c) * 72 + ks * 32 + q * 8];

    for (int t = blockIdx.x * 4 + wid; t < ntile; t += gridDim.x * 4) {
        const int e0 = s0 + (t << 4);
        const int ea = e0 + c;
        const int srcn = (ea < s1) ? ssrc[ea] : ssrc[e0];
        const unsigned short* xrow = xb + srcn * DD;
        s16x8 a0 = *(const s16x8*)(xrow + q * 8);
        s16x8 a1 = *(const s16x8*)(xrow + 32 + q * 8);

        f32x4 acc[4];
        #pragma unroll
        for (int nb = 0; nb < 4; ++nb) {
            f32x4 a = {0.f, 0.f, 0.f, 0.f};
            a = __builtin_amdgcn_mfma_f32_16x16x32_bf16(a0, bfrag[nb][0], a, 0, 0, 0);
            a = __builtin_amdgcn_mfma_f32_16x16x32_bf16(a1, bfrag[nb][1], a, 0, 0, 0);
            acc[nb] = a;
        }

        #pragma unroll
        for (int v = 0; v < 4; ++v) {
            const int er = e0 + q * 4 + v;
            if (er < s1) {
                const int dstn = sdst[er];
                float* op = out + dstn * DD + c;
                unsafeAtomicAdd(op +  0, acc[0][v]);
                unsafeAtomicAdd(op + 16, acc[1][v]);
                unsafeAtomicAdd(op + 32, acc[2][v]);
                unsafeAtomicAdd(op + 48, acc[3][v]);
            }
        }
    }
}

__global__ void relu_bf(float* __restrict__ buf, unsigned short* __restrict__ hb) {
    int i = blockIdx.x * blockDim.x + threadIdx.x;
    if (i >= NN * DD) return;
    float v = buf[i];
    v = v > 0.f ? v : 0.f;
    buf[i] = v;
    hb[i] = f2bf(v);
}

__global__ void relu_only(float* __restrict__ buf) {
    int i = blockIdx.x * blockDim.x + threadIdx.x;
    if (i >= NN * DD) return;
    float v = buf[i];
    buf[i] = v > 0.f ? v : 0.f;
}

// ================= launch =================

extern "C" void kernel_launch(void* const* d_in, const int* in_sizes, int n_in,
                              void* d_out, int out_size, void* d_ws, size_t ws_size,
                              hipStream_t stream)
{
    (void)in_sizes; (void)n_in; (void)out_size;
    const float* x    = (const float*)d_in[0];
    const int*   ei   = (const int*)d_in[1];
    const int*   et   = (const int*)d_in[2];
    const float* W1   = (const float*)d_in[3];
    const float* sw1  = (const float*)d_in[4];
    const float* b1   = (const float*)d_in[5];
    const float* W2   = (const float*)d_in[6];
    const float* sw2  = (const float*)d_in[7];
    const float* b2   = (const float*)d_in[8];
    float* out = (float*)d_out;

    const int* src = ei;
    const int* dst = ei + NE;

    char* ws = (char*)d_ws;

    // ---------- new-path workspace layout ----------
    const size_t off_tab  = 0;                       // 17*NN*64*2 = 217,600,000
    const size_t off_xb   = 217600000;               // 12,800,000
    const size_t off_h1b  = 230400000;               // 12,800,000
    const size_t off_wt2  = 243200000;               // 2*17*4096*2 = 278,528
    const size_t off_sg   = 243478528;               // 5,000,000
    const size_t off_rp   = 248478528;               // 400,004
    const size_t off_cur  = 248878544;               // 400,000
    const size_t off_cnt  = 249278544;               // 400,000
    const size_t off_part = 249678544;               // 1,564
    const size_t NEED     = 249680128;

    if (ws_size >= NEED) {
        unsigned short* tab  = (unsigned short*)(ws + off_tab);
        unsigned short* xb   = (unsigned short*)(ws + off_xb);
        unsigned short* h1b  = (unsigned short*)(ws + off_h1b);
        unsigned short* wt2  = (unsigned short*)(ws + off_wt2);
        int* sg   = (int*)(ws + off_sg);
        int* rp   = (int*)(ws + off_rp);
        int* cur  = (int*)(ws + off_cur);
        int* cnt  = (int*)(ws + off_cnt);
        int* part = (int*)(ws + off_part);

        const int NB_E    = (NE + 255) / 256;        // 4883
        const int NB_ELEM = (NN * DD + 255) / 256;   // 25000

        // sort edges by dst (once)
        hipMemsetAsync(cnt, 0, NN * sizeof(int), stream);
        hist_dst<<<NB_E, 256, 0, stream>>>(dst, cnt);
        scan1<<<NBLK_SCAN, 256, 0, stream>>>(cnt, rp, part);
        scan2<<<1, 512, 0, stream>>>(part, rp);
        scan3<<<NBLK_SCAN, 256, 0, stream>>>(rp, part, cur);
        scatter_dst<<<NB_E, 256, 0, stream>>>(src, dst, et, cur, sg);

        // precision prep
        prep_w2<<<(2 * NP * DD * DD + 255) / 256, 256, 0, stream>>>(W1, sw1, W2, sw2, wt2);
        prep_x2<<<NB_ELEM, 256, 0, stream>>>(x, xb);

        const int NB_XW  = (NTILE + 3) / 4;          // 1563
        const int NB_AGG = NN / 4;                   // 25000

        // ---- layer 1 ----
        xw_kernel<<<NB_XW, 256, 0, stream>>>(xb, wt2, tab);
        agg_kernel<<<NB_AGG, 256, 0, stream>>>(tab, rp, sg, b1, x, nullptr, h1b);

        // ---- layer 2 ----
        xw_kernel<<<NB_XW, 256, 0, stream>>>(h1b, wt2 + NP * DD * DD, tab);
        agg_kernel<<<NB_AGG, 256, 0, stream>>>(tab, rp, sg, b2, nullptr, out, nullptr);
        return;
    }

    // ---------- fallback: round-1 path ----------
    float*          acc1 = (float*)(ws);
    unsigned short* xb   = (unsigned short*)(ws + 25600000);
    unsigned short* h1b  = (unsigned short*)(ws + 38400000);
    unsigned short* wt   = (unsigned short*)(ws + 51200000);
    int*            ssrc = (int*)(ws + 51462144);
    int*            sdst = (int*)(ws + 56462144);
    int*            hist = (int*)(ws + 61462144);
    int*            base = (int*)(ws + 61462208);
    int*            off  = (int*)(ws + 61462272);

    const int NB_ELEM = (NN * DD + 255) / 256;

    zero_counters<<<1, 64, 0, stream>>>(hist);
    hist_kernel<<<512, 256, 0, stream>>>(et, hist);
    scan_kernel<<<1, 64, 0, stream>>>(hist, off, base);
    scatter_kernel<<<(NE + SCHUNK - 1) / SCHUNK, 256, 0, stream>>>(src, dst, et, base, ssrc, sdst);

    prep_w<<<(2 * RR * DD * DD + 255) / 256, 256, 0, stream>>>(W1, W2, wt);
    prep_x2<<<NB_ELEM, 256, 0, stream>>>(x, xb);

    self_kernel<<<NB_ELEM, 256, 0, stream>>>(x, sw1, b1, acc1, 1);
    edge_kernel<<<dim3(128, RR), 256, 0, stream>>>(xb, wt, ssrc, sdst, off, acc1);
    relu_bf<<<NB_ELEM, 256, 0, stream>>>(acc1, h1b);

    self_kernel<<<NB_ELEM, 256, 0, stream>>>(acc1, sw2, b2, out, 0);
    edge_kernel<<<dim3(128, RR), 256, 0, stream>>>(h1b, wt + RR * DD * DD, ssrc, sdst, off, out);
    relu_only<<<NB_ELEM, 256, 0, stream>>>(out);
}

// Round 3
// 598.210 us; speedup vs baseline: 1.4406x; 1.0233x over previous
//
#include <hip/hip_runtime.h>
#include <hip/hip_bf16.h>

#define NN 100000
#define NE 1250000
#define DD 64
#define RR 16
#define NP 17            // 16 relations + self plane
#define NTILE 6250       // NN/16

typedef __attribute__((ext_vector_type(8))) short s16x8;
typedef __attribute__((ext_vector_type(4))) float f32x4;

static __device__ __forceinline__ unsigned short f2bf(float v) {
    __hip_bfloat16 h = __float2bfloat16(v);
    return __builtin_bit_cast(unsigned short, h);
}
static __device__ __forceinline__ float bf2f(unsigned short u) {
    unsigned int w = ((unsigned int)u) << 16;
    return __builtin_bit_cast(float, w);
}
static __device__ __forceinline__ unsigned int pack2(float a, float b) {
    return ((unsigned int)f2bf(b) << 16) | (unsigned int)f2bf(a);
}

// ---------------- sort by dst (counting sort, 100k bins) ----------------

__global__ void hist_dst(const int* __restrict__ dst, int* __restrict__ cnt) {
    int e = blockIdx.x * 256 + threadIdx.x;
    if (e < NE) atomicAdd(&cnt[dst[e]], 1);
}

__global__ __launch_bounds__(256) void scan1(const int* __restrict__ cnt,
                                             int* __restrict__ rp, int* __restrict__ part) {
    __shared__ int s[256];
    int i = blockIdx.x * 256 + threadIdx.x;
    int v = (i < NN) ? cnt[i] : 0;
    s[threadIdx.x] = v;
    __syncthreads();
    for (int off = 1; off < 256; off <<= 1) {
        int t = (threadIdx.x >= off) ? s[threadIdx.x - off] : 0;
        __syncthreads();
        s[threadIdx.x] += t;
        __syncthreads();
    }
    if (i < NN) rp[i] = s[threadIdx.x] - v;           // exclusive
    if (threadIdx.x == 255) part[blockIdx.x] = s[255];
}

#define NBLK_SCAN 391   // ceil(NN/256)
__global__ void scan2(int* __restrict__ part, int* __restrict__ rp) {
    __shared__ int s[NBLK_SCAN];
    if (threadIdx.x < NBLK_SCAN) s[threadIdx.x] = part[threadIdx.x];
    __syncthreads();
    if (threadIdx.x == 0) {
        int acc = 0;
        for (int b = 0; b < NBLK_SCAN; ++b) { int t = s[b]; s[b] = acc; acc += t; }
        rp[NN] = NE;
    }
    __syncthreads();
    if (threadIdx.x < NBLK_SCAN) part[threadIdx.x] = s[threadIdx.x];
}

__global__ void scan3(int* __restrict__ rp, const int* __restrict__ part, int* __restrict__ cur) {
    int i = blockIdx.x * 256 + threadIdx.x;
    if (i < NN) {
        int v = rp[i] + part[blockIdx.x];
        rp[i] = v;
        cur[i] = v;
    }
}

// sg[p] = rel*NN + src   (row index into the [plane][n] table)
__global__ void scatter_dst(const int* __restrict__ src, const int* __restrict__ dst,
                            const int* __restrict__ et, int* __restrict__ cur,
                            int* __restrict__ sg) {
    int e = blockIdx.x * 256 + threadIdx.x;
    if (e >= NE) return;
    int p = atomicAdd(&cur[dst[e]], 1);
    sg[p] = et[e] * NN + src[e];
}

// ---------------- precision prep ----------------

// wt2[l][p][o][d] = bf16( (p<16 ? W_l[p] : sw_l)[d][o] )
__global__ void prep_w2(const float* __restrict__ W1, const float* __restrict__ sw1,
                        const float* __restrict__ W2, const float* __restrict__ sw2,
                        unsigned short* __restrict__ wt) {
    int i = blockIdx.x * 256 + threadIdx.x;
    if (i >= 2 * NP * DD * DD) return;
    int d = i & 63;
    int o = (i >> 6) & 63;
    int p = (i >> 12) % NP;
    int l = i / (NP * DD * DD);
    const float* src;
    if (p < 16) src = (l ? W2 : W1) + p * DD * DD;
    else        src = (l ? sw2 : sw1);
    wt[i] = f2bf(src[d * DD + o]);
}

__global__ void prep_x2(const float* __restrict__ x, unsigned short* __restrict__ xb) {
    int i = blockIdx.x * blockDim.x + threadIdx.x;
    if (i < NN * DD) xb[i] = f2bf(x[i]);
}

// ---------------- kernel A: dense table  xW[p][n][o] ----------------
// Transposed compute: C = Wp^T (A, m=o) x X^T (B, n=node), so each lane owns
// 4 consecutive o-values -> packed 8B stores instead of 16 scattered u16 stores.
__global__ __launch_bounds__(256) void xw_kernel(
    const unsigned short* __restrict__ xb,   // [N][64] bf16  (B: [k=d][n=node])
    const unsigned short* __restrict__ wt,   // [17][64][64] bf16 (A: [m=o][k=d])
    unsigned short* __restrict__ tab)        // [17][N][64] bf16
{
    const int wid  = threadIdx.x >> 6;
    const int lane = threadIdx.x & 63;
    const int c = lane & 15;       // node within tile (B col / C col)
    const int q = lane >> 4;
    const int t = blockIdx.x * 4 + wid;
    if (t >= NTILE) return;
    const int n0 = t * 16;
    const int p0 = blockIdx.y * 4;
    const int p1 = min(p0 + 4, NP);

    // B fragments from x (shared across planes and o-blocks)
    const unsigned short* xrow = xb + (size_t)(n0 + c) * DD + q * 8;
    s16x8 b0 = *(const s16x8*)(xrow);
    s16x8 b1 = *(const s16x8*)(xrow + 32);

    for (int p = p0; p < p1; ++p) {
        const unsigned short* wp = wt + p * (DD * DD);
        uint2* orow = (uint2*)(tab + ((size_t)p * NN + n0 + c) * DD);
        #pragma unroll
        for (int nb = 0; nb < 4; ++nb) {
            const unsigned short* wrow = wp + (nb * 16 + c) * DD + q * 8;
            s16x8 a0 = *(const s16x8*)(wrow);
            s16x8 a1 = *(const s16x8*)(wrow + 32);
            f32x4 acc = {0.f, 0.f, 0.f, 0.f};
            acc = __builtin_amdgcn_mfma_f32_16x16x32_bf16(a0, b0, acc, 0, 0, 0);
            acc = __builtin_amdgcn_mfma_f32_16x16x32_bf16(a1, b1, acc, 0, 0, 0);
            // C: row (o within block) = q*4+v, col (node) = c
            uint2 pk;
            pk.x = pack2(acc[0], acc[1]);
            pk.y = pack2(acc[2], acc[3]);
            orow[nb * 4 + q] = pk;   // o = nb*16 + q*4, 8B aligned
        }
    }
}

// ---------------- kernel B: per-dst segment sum + self + bias (+res) + relu ----
// Half-wave per edge: lane loads uint (2 bf16), halves combined via shfl_xor.
__global__ __launch_bounds__(256) void agg_kernel(
    const unsigned short* __restrict__ tab,  // [17][N][64] bf16
    const int* __restrict__ rp,              // [N+1]
    const int* __restrict__ sg,              // [E] row index = rel*NN+src
    const float* __restrict__ bias,
    const float* __restrict__ xres,          // residual (fp32) or nullptr
    float* __restrict__ outf,                // fp32 out (layer 2) or nullptr
    unsigned short* __restrict__ outb)       // bf16 out (layer 1) or nullptr
{
    const int wid  = threadIdx.x >> 6;
    const int lane = threadIdx.x & 63;
    const int n = blockIdx.x * 4 + wid;      // 25000*4 == NN exactly
    const int h  = lane >> 5;                // half-wave id (edge parity)
    const int ol = lane & 31;                // o-pair index: o = 2*ol, 2*ol+1

    float a0 = 0.f, a1 = 0.f;
    int e = rp[n];
    const int e1 = rp[n + 1];
    for (; e + 4 <= e1; e += 4) {
        int r0 = sg[e + h];
        int r1 = sg[e + 2 + h];
        unsigned int u0 = *(const unsigned int*)(tab + (size_t)r0 * DD + ol * 2);
        unsigned int u1 = *(const unsigned int*)(tab + (size_t)r1 * DD + ol * 2);
        a0 += bf2f((unsigned short)u0) + bf2f((unsigned short)u1);
        a1 += bf2f((unsigned short)(u0 >> 16)) + bf2f((unsigned short)(u1 >> 16));
    }
    for (; e + 2 <= e1; e += 2) {
        int r0 = sg[e + h];
        unsigned int u0 = *(const unsigned int*)(tab + (size_t)r0 * DD + ol * 2);
        a0 += bf2f((unsigned short)u0);
        a1 += bf2f((unsigned short)(u0 >> 16));
    }
    if (e < e1 && h == 0) {
        int r0 = sg[e];
        unsigned int u0 = *(const unsigned int*)(tab + (size_t)r0 * DD + ol * 2);
        a0 += bf2f((unsigned short)u0);
        a1 += bf2f((unsigned short)(u0 >> 16));
    }
    // combine the two halves
    a0 += __shfl_xor(a0, 32, 64);
    a1 += __shfl_xor(a1, 32, 64);

    // self plane + bias (+ residual)
    {
        unsigned int u = *(const unsigned int*)(tab + ((size_t)16 * NN + n) * DD + ol * 2);
        a0 += bf2f((unsigned short)u);
        a1 += bf2f((unsigned short)(u >> 16));
    }
    const float2 bv = *(const float2*)(bias + ol * 2);
    a0 += bv.x; a1 += bv.y;
    if (xres) {
        const float2 rv = *(const float2*)(xres + (size_t)n * DD + ol * 2);
        a0 += rv.x; a1 += rv.y;
    }
    a0 = fmaxf(a0, 0.f);
    a1 = fmaxf(a1, 0.f);

    if (h == 0) {
        if (outb)
            *(unsigned int*)(outb + (size_t)n * DD + ol * 2) = pack2(a0, a1);
        if (outf) {
            float2 v = {a0, a1};
            *(float2*)(outf + (size_t)n * DD + ol * 2) = v;
        }
    }
}

// ================= launch =================

extern "C" void kernel_launch(void* const* d_in, const int* in_sizes, int n_in,
                              void* d_out, int out_size, void* d_ws, size_t ws_size,
                              hipStream_t stream)
{
    (void)in_sizes; (void)n_in; (void)out_size; (void)ws_size;
    const float* x    = (const float*)d_in[0];
    const int*   ei   = (const int*)d_in[1];
    const int*   et   = (const int*)d_in[2];
    const float* W1   = (const float*)d_in[3];
    const float* sw1  = (const float*)d_in[4];
    const float* b1   = (const float*)d_in[5];
    const float* W2   = (const float*)d_in[6];
    const float* sw2  = (const float*)d_in[7];
    const float* b2   = (const float*)d_in[8];
    float* out = (float*)d_out;

    const int* src = ei;
    const int* dst = ei + NE;

    char* ws = (char*)d_ws;

    // workspace layout (needs ~250 MB; verified available in round 2)
    unsigned short* tab  = (unsigned short*)(ws);                 // 217,600,000
    unsigned short* xb   = (unsigned short*)(ws + 217600000);     //  12,800,000
    unsigned short* h1b  = (unsigned short*)(ws + 230400000);     //  12,800,000
    unsigned short* wt2  = (unsigned short*)(ws + 243200000);     //     278,528
    int* sg   = (int*)(ws + 243478528);                           //   5,000,000
    int* rp   = (int*)(ws + 248478528);                           //     400,004
    int* cur  = (int*)(ws + 248878544);                           //     400,000
    int* cnt  = (int*)(ws + 249278544);                           //     400,000
    int* part = (int*)(ws + 249678544);                           //       1,564

    const int NB_E    = (NE + 255) / 256;        // 4883
    const int NB_ELEM = (NN * DD + 255) / 256;   // 25000

    // sort edges by dst (once; reused by both layers)
    hipMemsetAsync(cnt, 0, NN * sizeof(int), stream);
    hist_dst<<<NB_E, 256, 0, stream>>>(dst, cnt);
    scan1<<<NBLK_SCAN, 256, 0, stream>>>(cnt, rp, part);
    scan2<<<1, 512, 0, stream>>>(part, rp);
    scan3<<<NBLK_SCAN, 256, 0, stream>>>(rp, part, cur);
    scatter_dst<<<NB_E, 256, 0, stream>>>(src, dst, et, cur, sg);

    // precision prep
    prep_w2<<<(2 * NP * DD * DD + 255) / 256, 256, 0, stream>>>(W1, sw1, W2, sw2, wt2);
    prep_x2<<<NB_ELEM, 256, 0, stream>>>(x, xb);

    const int NB_XW  = (NTILE + 3) / 4;          // 1563
    const int NB_AGG = NN / 4;                   // 25000

    // ---- layer 1 (residual) ----
    xw_kernel<<<dim3(NB_XW, 5), 256, 0, stream>>>(xb, wt2, tab);
    agg_kernel<<<NB_AGG, 256, 0, stream>>>(tab, rp, sg, b1, x, nullptr, h1b);

    // ---- layer 2 (no residual) ----
    xw_kernel<<<dim3(NB_XW, 5), 256, 0, stream>>>(h1b, wt2 + NP * DD * DD, tab);
    agg_kernel<<<NB_AGG, 256, 0, stream>>>(tab, rp, sg, b2, nullptr, out, nullptr);
}